// Round 1
// baseline (991.933 us; speedup 1.0000x reference)
//
#include <hip/hip_runtime.h>

// Spatial correlation sampler: out[b, dh*9+dw, h, w] =
//   (1/C) * sum_c in1[b,c,h,w] * in2[b,c,h+dh-4,w+dw-4]   (zero-padded)
// B=8 C=256 H=128 W=256, patch 9x9 (RADIUS=4), fp32 in/out.

#define RADIUS 4
#define PSZ    9
#define NP     81

#define Bdim 8
#define Cdim 256
#define Hdim 128
#define Wdim 256
#define HWs  (Hdim * Wdim)

#define TW 32                    // tile width  (outputs per block)
#define TH 8                     // tile height (outputs per block)
#define HALO_W (TW + 2 * RADIUS) // 40
#define HALO_H (TH + 2 * RADIUS) // 16
#define CK 8                     // channels staged per chunk
#define NT 192                   // 3 waves: wave i handles dh in {3i, 3i+1, 3i+2}

__global__ __launch_bounds__(NT, 3)
void corr81(const float* __restrict__ in1, const float* __restrict__ in2,
            float* __restrict__ out)
{
    // 8*16*40*4 = 20.5 KB; 4 blocks/CU -> 82 KB of 160 KB
    __shared__ float s2[CK][HALO_H][HALO_W];

    const int tid = threadIdx.x;
    const int tw  = tid & 7;          // w-subtile: 4 floats each
    const int th  = (tid >> 3) & 7;   // row within tile
    const int dhg = tid >> 6;         // wave id = dh group (0..2)

    const int w0 = blockIdx.x * TW;
    const int h0 = blockIdx.y * TH;
    const int b  = blockIdx.z;

    const int hh = h0 + th;
    const int ww = w0 + 4 * tw;

    const float* in1p = in1 + (size_t)b * Cdim * HWs + (size_t)hh * Wdim + ww;
    const float* in2b = in2 + (size_t)b * Cdim * HWs;

    float acc[3][PSZ][4];
#pragma unroll
    for (int i = 0; i < 3; ++i)
#pragma unroll
        for (int d = 0; d < PSZ; ++d)
#pragma unroll
            for (int j = 0; j < 4; ++j) acc[i][d][j] = 0.f;

    for (int c0 = 0; c0 < Cdim; c0 += CK) {
        __syncthreads();
        // ---- stage in2 halo (16x40) for CK channels into LDS ----
        for (int idx = tid; idx < CK * HALO_H * HALO_W; idx += NT) {
            const int cc  = idx / (HALO_H * HALO_W);
            const int rem = idx - cc * (HALO_H * HALO_W);
            const int ry  = rem / HALO_W;
            const int cx  = rem - ry * HALO_W;
            const int gr  = h0 - RADIUS + ry;
            const int gc  = w0 - RADIUS + cx;
            float v = 0.f;
            if ((unsigned)gr < (unsigned)Hdim && (unsigned)gc < (unsigned)Wdim)
                v = in2b[(size_t)(c0 + cc) * HWs + gr * Wdim + gc];
            s2[cc][ry][cx] = v;
        }
        __syncthreads();

        // ---- compute: 108 FMAs per channel per thread ----
        const float* p1 = in1p + (size_t)c0 * HWs;
        float4 cur = *(const float4*)p1;
#pragma unroll
        for (int cc = 0; cc < CK; ++cc) {
            float4 nxt = cur;  // software-pipeline next channel's in1
            if (c0 + cc + 1 < Cdim) nxt = *(const float4*)(p1 + (size_t)(cc + 1) * HWs);
            const float a0 = cur.x, a1 = cur.y, a2 = cur.z, a3 = cur.w;
#pragma unroll
            for (int i = 0; i < 3; ++i) {
                const int dh = dhg * 3 + i;
                // halo row = th + dh (global row h0+th+dh-4), cols 4tw..4tw+11
                const float* rowp = &s2[cc][th + dh][4 * tw];
                const float4 wa = *(const float4*)(rowp);
                const float4 wb = *(const float4*)(rowp + 4);
                const float4 wc = *(const float4*)(rowp + 8);
                const float win[12] = {wa.x, wa.y, wa.z, wa.w,
                                       wb.x, wb.y, wb.z, wb.w,
                                       wc.x, wc.y, wc.z, wc.w};
#pragma unroll
                for (int dw = 0; dw < PSZ; ++dw) {
                    acc[i][dw][0] = fmaf(a0, win[dw + 0], acc[i][dw][0]);
                    acc[i][dw][1] = fmaf(a1, win[dw + 1], acc[i][dw][1]);
                    acc[i][dw][2] = fmaf(a2, win[dw + 2], acc[i][dw][2]);
                    acc[i][dw][3] = fmaf(a3, win[dw + 3], acc[i][dw][3]);
                }
            }
            cur = nxt;
        }
    }

    // ---- epilogue: 27 float4 stores per thread ----
    const float scale = 1.0f / (float)Cdim;
#pragma unroll
    for (int i = 0; i < 3; ++i) {
        const int dh = dhg * 3 + i;
#pragma unroll
        for (int dw = 0; dw < PSZ; ++dw) {
            const int p = dh * PSZ + dw;
            float4 o;
            o.x = acc[i][dw][0] * scale;
            o.y = acc[i][dw][1] * scale;
            o.z = acc[i][dw][2] * scale;
            o.w = acc[i][dw][3] * scale;
            *(float4*)(out + (((size_t)b * NP + p) * Hdim + hh) * Wdim + ww) = o;
        }
    }
}

extern "C" void kernel_launch(void* const* d_in, const int* in_sizes, int n_in,
                              void* d_out, int out_size, void* d_ws, size_t ws_size,
                              hipStream_t stream)
{
    const float* in1 = (const float*)d_in[0];
    const float* in2 = (const float*)d_in[1];
    float* out = (float*)d_out;
    dim3 grid(Wdim / TW, Hdim / TH, Bdim);
    corr81<<<grid, NT, 0, stream>>>(in1, in2, out);
}